// Round 4
// baseline (919.166 us; speedup 1.0000x reference)
//
#include <hip/hip_runtime.h>
#include <hip/hip_bf16.h>
#include <math.h>
#include <stdint.h>

// Problem constants (B=4, S=2048, H=1024, I=4096, E=8, K=2)
#define TOKENS 8192
#define HD 1024
#define ID 4096
#define NE 8
#define RMAX 18432   // 16384 + 8*256 worst-case padded rows (experts padded to 256)
#define MAXT 72      // RMAX/256 max M-tiles

typedef __attribute__((ext_vector_type(8))) short short8v;
typedef __attribute__((ext_vector_type(4))) float f32x4;

typedef const __attribute__((address_space(1))) unsigned int* gas_u32p;
typedef __attribute__((address_space(3))) unsigned int* las_u32p;

__device__ __forceinline__ void stage16(const void* g, void* l) {
  __builtin_amdgcn_global_load_lds((gas_u32p)g, (las_u32p)l, 16, 0, 0);
}

#define BARRIER asm volatile("s_barrier" ::: "memory")
#define WAITLGKM asm volatile("s_waitcnt lgkmcnt(0)" ::: "memory")
#define VMC0 asm volatile("s_waitcnt vmcnt(0)" ::: "memory")
#define VMC2 asm volatile("s_waitcnt vmcnt(2)" ::: "memory")
#define VMC6 asm volatile("s_waitcnt vmcnt(6)" ::: "memory")
#define VMC8 asm volatile("s_waitcnt vmcnt(8)" ::: "memory")

// ---------------- weight fp32 -> bf16 convert (all 3 arrays, 1 launch) ----------------
// wg/wu/wd are allocated contiguously in ws (each 64MB, 256B-aligned) so one dst base works.
__global__ __launch_bounds__(256) void convert3_kernel(
    const float* __restrict__ s0, const float* __restrict__ s1, const float* __restrict__ s2,
    __hip_bfloat16* __restrict__ d0) {
  int r = blockIdx.x >> 14;  // 16384 blocks per region
  const float* src = (r == 0) ? s0 : ((r == 1) ? s1 : s2);
  __hip_bfloat16* dst = d0 + (size_t)r * ((size_t)NE * ID * HD);
  size_t i = (((size_t)(blockIdx.x & 16383)) * 256 + threadIdx.x) * 8;
  float4 a = ((const float4*)(src + i))[0];
  float4 b = ((const float4*)(src + i))[1];
  union { __hip_bfloat16 h[8]; int4 v; } u;
  u.h[0] = __float2bfloat16(a.x); u.h[1] = __float2bfloat16(a.y);
  u.h[2] = __float2bfloat16(a.z); u.h[3] = __float2bfloat16(a.w);
  u.h[4] = __float2bfloat16(b.x); u.h[5] = __float2bfloat16(b.y);
  u.h[6] = __float2bfloat16(b.z); u.h[7] = __float2bfloat16(b.w);
  *(int4*)(dst + i) = u.v;
}

// ---------------- router: logits (fp64 acc), top-2, weights; also h->bf16 ----------------
__global__ __launch_bounds__(256) void router_kernel(
    const float* __restrict__ h, const float* __restrict__ rw,
    __hip_bfloat16* __restrict__ hx, int* __restrict__ tidx,
    float* __restrict__ tw, int* __restrict__ cnt) {
  int wid = threadIdx.x >> 6, lane = threadIdx.x & 63;
  int t = blockIdx.x * 4 + wid;  // grid = TOKENS/4
  const float4* h4 = (const float4*)(h + (size_t)t * HD);
  float x[16];
  {
    float4 xa = h4[lane * 4 + 0], xb = h4[lane * 4 + 1], xc = h4[lane * 4 + 2], xd = h4[lane * 4 + 3];
    x[0] = xa.x; x[1] = xa.y; x[2] = xa.z; x[3] = xa.w;
    x[4] = xb.x; x[5] = xb.y; x[6] = xb.z; x[7] = xb.w;
    x[8] = xc.x; x[9] = xc.y; x[10] = xc.z; x[11] = xc.w;
    x[12] = xd.x; x[13] = xd.y; x[14] = xd.z; x[15] = xd.w;
  }
  union { __hip_bfloat16 hb[16]; int4 v[2]; } u;
#pragma unroll
  for (int j = 0; j < 16; j++) u.hb[j] = __float2bfloat16(x[j]);
  {
    int4* hxp = (int4*)(hx + (size_t)t * HD + lane * 16);
    hxp[0] = u.v[0]; hxp[1] = u.v[1];
  }
  double acc[NE];
#pragma unroll
  for (int e = 0; e < NE; e++) {
    const float4* w4 = (const float4*)(rw + e * HD);
    float4 wa = w4[lane * 4 + 0], wb = w4[lane * 4 + 1], wc = w4[lane * 4 + 2], wd = w4[lane * 4 + 3];
    double s = 0.0;
    s += (double)x[0] * wa.x + (double)x[1] * wa.y + (double)x[2] * wa.z + (double)x[3] * wa.w;
    s += (double)x[4] * wb.x + (double)x[5] * wb.y + (double)x[6] * wb.z + (double)x[7] * wb.w;
    s += (double)x[8] * wc.x + (double)x[9] * wc.y + (double)x[10] * wc.z + (double)x[11] * wc.w;
    s += (double)x[12] * wd.x + (double)x[13] * wd.y + (double)x[14] * wd.z + (double)x[15] * wd.w;
    acc[e] = s;
  }
#pragma unroll
  for (int off = 32; off >= 1; off >>= 1)
#pragma unroll
    for (int e = 0; e < NE; e++) acc[e] += __shfl_xor(acc[e], off, 64);
  if (lane == 0) {
    int i0 = 0; double l0 = acc[0];
#pragma unroll
    for (int e = 1; e < NE; e++) if (acc[e] > l0) { l0 = acc[e]; i0 = e; }
    int i1 = -1; double l1 = -1.0e300;
#pragma unroll
    for (int e = 0; e < NE; e++) if (e != i0 && acc[e] > l1) { l1 = acc[e]; i1 = e; }
    double r = exp(l1 - l0);  // <= 1
    float w0 = (float)(1.0 / (1.0 + r));
    float w1 = (float)(r / (1.0 + r));
    tidx[t * 2 + 0] = i0; tidx[t * 2 + 1] = i1;
    tw[t * 2 + 0] = w0;  tw[t * 2 + 1] = w1;
    atomicAdd(&cnt[i0], 1); atomicAdd(&cnt[i1], 1);
  }
}

// ---------------- offsets scan (pad each expert to 256 rows) ----------------
__global__ void scan_kernel(const int* __restrict__ cnt, int* __restrict__ ofs, int* __restrict__ cnt2) {
  if (threadIdx.x == 0) {
    int a = 0;
    for (int e = 0; e < NE; e++) { ofs[e] = a; a += (cnt[e] + 255) & ~255; }
    ofs[NE] = a;
  }
  if (threadIdx.x < NE) cnt2[threadIdx.x] = 0;
}

// ---------------- scatter token -> expert row lists ----------------
__global__ __launch_bounds__(256) void scatter_kernel(
    const int* __restrict__ tidx, const float* __restrict__ tw,
    const int* __restrict__ ofs, int* __restrict__ cnt2,
    int* __restrict__ rowmap, int* __restrict__ slots) {
  int t = blockIdx.x * 256 + threadIdx.x;  // grid = TOKENS/256
#pragma unroll
  for (int k = 0; k < 2; k++) {
    int e = tidx[t * 2 + k];
    int pos = atomicAdd(&cnt2[e], 1);
    int row = ofs[e] + pos;
    rowmap[row] = t;
    slots[t * 2 + k] = row;
  }
}

// Full 4x4x2 MFMA block: 32 MFMA
#define MFMA44(ACC, AF, BF)                                                                \
  { _Pragma("unroll") for (int m_ = 0; m_ < 4; m_++)                                       \
    _Pragma("unroll") for (int n_ = 0; n_ < 4; n_++)                                       \
    _Pragma("unroll") for (int k_ = 0; k_ < 2; k_++)                                       \
      ACC[m_][n_] = __builtin_amdgcn_mfma_f32_16x16x32_bf16(                               \
          AF[m_][k_], BF[n_][k_], ACC[m_][n_], 0, 0, 0); }

// =================== GEMM1 (fused gate+up+silu), 256x128 tile, 4-phase/2-Ktiles ==========
// A-panel staged DIRECTLY from hx via rowmap (per-lane global source); pad rows read zrow.
// LDS: per buffer 64KB: A[256x64] @0, G[128x64] @32768, U[128x64] @49152; x2 buffers.
// Phases per iter (t0->buf0, t0+1->buf1):
//  PA: read buf0 A+G (16), stage U(t0+1)->buf1 [2],  32 MFMA accG, VMC8
//  PB: read buf0 U (8),    stage A,G(t0+2)->buf0 [6], 32 MFMA accU, VMC8 (tail VMC2)
//  PC: read buf1 A+G (16), stage U(t0+2)->buf0 [2],  32 MFMA accG, VMC8 (tail VMC0)
//  PD: read buf1 U (8),    stage A,G(t0+3)->buf1 [6], 32 MFMA accU, VMC8 (tail VMC0)
// Ledger: steady-state 8 in flight after each phase-end VMC8; each VMC8 drains exactly
// the group needed two phases later. Write-after-read gap >= 1 phase everywhere.
__global__ __launch_bounds__(512, 2) void gemm1_kernel(
    const __hip_bfloat16* __restrict__ hx, const __hip_bfloat16* __restrict__ Wg,
    const __hip_bfloat16* __restrict__ Wu, const int* __restrict__ rowmap,
    const int* __restrict__ ofs, const __hip_bfloat16* __restrict__ zrow,
    __hip_bfloat16* __restrict__ act) {
  __shared__ __align__(128) char lds[131072];
  const int nwg = gridDim.x;              // 2304 (div by 8)
  int wg0 = blockIdx.x;
  int wg = (wg0 & 7) * (nwg >> 3) + (wg0 >> 3);  // XCD-chunked swizzle
  const int tm = wg >> 5, tn = wg & 31;   // NTN = 32
  const int Rtot = ofs[NE];
  const int row0 = tm * 256;
  if (row0 >= Rtot) return;
  int e = 0;
#pragma unroll
  for (int i = 1; i < NE; i++) e += (row0 >= ofs[i]);
  const int tid = threadIdx.x, wid = tid >> 6, lane = tid & 63;
  const int wm = wid >> 1, wn = wid & 1;  // 4 M-warps x 2 N-warps
  const int fr = lane & 15, fkE = (lane >> 4) << 3;
  const int wmB = wm * 64, wnB = wn * 64;

  // stage source addresses (pre-swizzled global so linear global_load_lds dest = swizzled layout)
  const char* srcA[4]; const char* srcG[2]; const char* srcU[2];
  int ldA[4], ldG[2], ldU[2];
#pragma unroll
  for (int j = 0; j < 4; j++) {
    int d = j * 8192 + tid * 16;
    int row = d >> 7;
    int kb = (d ^ (((d >> 7) & 7) << 4)) & 127;
    int tok = rowmap[row0 + row];
    const __hip_bfloat16* base = (tok >= 0) ? (hx + (size_t)tok * HD) : zrow;
    srcA[j] = (const char*)base + kb;
    ldA[j] = j * 8192 + wid * 1024;
  }
#pragma unroll
  for (int j = 0; j < 2; j++) {
    int d = j * 8192 + tid * 16;
    int row = d >> 7;
    int kb = (d ^ (((d >> 7) & 7) << 4)) & 127;
    srcG[j] = (const char*)(Wg + ((size_t)e * ID + tn * 128 + row) * HD) + kb;
    srcU[j] = (const char*)(Wu + ((size_t)e * ID + tn * 128 + row) * HD) + kb;
    ldG[j] = 32768 + j * 8192 + wid * 1024;
    ldU[j] = 49152 + j * 8192 + wid * 1024;
  }
#define STG_A(j, t, bf) stage16(srcA[j] + (size_t)(t) * 128, (char*)lds + (bf) * 65536 + ldA[j])
#define STG_G(j, t, bf) stage16(srcG[j] + (size_t)(t) * 128, (char*)lds + (bf) * 65536 + ldG[j])
#define STG_U(j, t, bf) stage16(srcU[j] + (size_t)(t) * 128, (char*)lds + (bf) * 65536 + ldU[j])

  auto RD = [&](int bf, int poff, int rowi, int kki) -> short8v {
    int o = ((rowi + fr) << 7) + ((kki << 5) + fkE) * 2;
    o ^= ((o >> 7) & 7) << 4;  // st swizzle (matches staged layout)
    return *(const short8v*)(&lds[bf * 65536 + poff + o]);
  };

  f32x4 accG[4][4], accU[4][4];
#pragma unroll
  for (int m = 0; m < 4; m++)
#pragma unroll
    for (int n = 0; n < 4; n++) { accG[m][n] = (f32x4)(0.0f); accU[m][n] = (f32x4)(0.0f); }

  const int NT = HD / 64;  // 16 K-tiles
  // prologue: A(0),G(0) -> buf0 [6]; U(0) -> buf0 [2]; A(1),G(1) -> buf1 [6]
#pragma unroll
  for (int j = 0; j < 4; j++) STG_A(j, 0, 0);
  STG_G(0, 0, 0); STG_G(1, 0, 0);
  STG_U(0, 0, 0); STG_U(1, 0, 0);
#pragma unroll
  for (int j = 0; j < 4; j++) STG_A(j, 1, 1);
  STG_G(0, 1, 1); STG_G(1, 1, 1);
  VMC8; BARRIER;

#pragma unroll 1
  for (int I = 0; I < NT / 2; ++I) {
    const int t0 = 2 * I;
    const bool more = (t0 + 2 < NT);
    short8v a[4][2], b[4][2];
    // ---- PA: buf0 A+G -> accG; stage U(t0+1)->buf1 ----
#pragma unroll
    for (int m = 0; m < 4; m++) { a[m][0] = RD(0, 0, wmB + m * 16, 0); a[m][1] = RD(0, 0, wmB + m * 16, 1); }
#pragma unroll
    for (int n = 0; n < 4; n++) { b[n][0] = RD(0, 32768, wnB + n * 16, 0); b[n][1] = RD(0, 32768, wnB + n * 16, 1); }
    STG_U(0, t0 + 1, 1); STG_U(1, t0 + 1, 1);
    BARRIER; WAITLGKM;
    __builtin_amdgcn_s_setprio(1); MFMA44(accG, a, b); __builtin_amdgcn_s_setprio(0);
    VMC8; BARRIER;
    // ---- PB: buf0 U -> accU; stage A,G(t0+2)->buf0 ----
#pragma unroll
    for (int n = 0; n < 4; n++) { b[n][0] = RD(0, 49152, wnB + n * 16, 0); b[n][1] = RD(0, 49152, wnB + n * 16, 1); }
    if (more) {
      STG_A(0, t0 + 2, 0); STG_A(1, t0 + 2, 0); STG_A(2, t0 + 2, 0); STG_A(3, t0 + 2, 0);
      STG_G(0, t0 + 2, 0); STG_G(1, t0 + 2, 0);
    }
    BARRIER; WAITLGKM;
    __builtin_amdgcn_s_setprio(1); MFMA44(accU, a, b); __builtin_amdgcn_s_setprio(0);
    if (more) { VMC8; } else { VMC2; }
    BARRIER;
    // ---- PC: buf1 A+G -> accG; stage U(t0+2)->buf0 ----
#pragma unroll
    for (int m = 0; m < 4; m++) { a[m][0] = RD(1, 0, wmB + m * 16, 0); a[m][1] = RD(1, 0, wmB + m * 16, 1); }
#pragma unroll
    for (int n = 0; n < 4; n++) { b[n][0] = RD(1, 32768, wnB + n * 16, 0); b[n][1] = RD(1, 32768, wnB + n * 16, 1); }
    if (more) { STG_U(0, t0 + 2, 0); STG_U(1, t0 + 2, 0); }
    BARRIER; WAITLGKM;
    __builtin_amdgcn_s_setprio(1); MFMA44(accG, a, b); __builtin_amdgcn_s_setprio(0);
    if (more) { VMC8; } else { VMC0; }
    BARRIER;
    // ---- PD: buf1 U -> accU; stage A,G(t0+3)->buf1 ----
#pragma unroll
    for (int n = 0; n < 4; n++) { b[n][0] = RD(1, 49152, wnB + n * 16, 0); b[n][1] = RD(1, 49152, wnB + n * 16, 1); }
    if (more) {
      STG_A(0, t0 + 3, 1); STG_A(1, t0 + 3, 1); STG_A(2, t0 + 3, 1); STG_A(3, t0 + 3, 1);
      STG_G(0, t0 + 3, 1); STG_G(1, t0 + 3, 1);
    }
    BARRIER; WAITLGKM;
    __builtin_amdgcn_s_setprio(1); MFMA44(accU, a, b); __builtin_amdgcn_s_setprio(0);
    if (more) { VMC8; } else { VMC0; }
    BARRIER;
  }
#undef STG_A
#undef STG_G
#undef STG_U

  // epilogue: act = bf16(silu(g) * u). C layout: col=lane&15, row=(lane>>4)*4+i.
  const int rb = row0 + wmB + ((lane >> 4) << 2);
  const int cb = tn * 128 + wnB + fr;
#pragma unroll
  for (int m = 0; m < 4; m++)
#pragma unroll
    for (int i = 0; i < 4; i++) {
      int r = rb + m * 16 + i;
      __hip_bfloat16* dst = act + (size_t)r * ID + cb;
#pragma unroll
      for (int n = 0; n < 4; n++) {
        float g = accG[m][n][i], uu = accU[m][n][i];
        float s = g / (1.0f + __expf(-g));
        dst[n * 16] = __float2bfloat16(s * uu);
      }
    }
}

// =================== GEMM2: y = act @ Wd[e]^T, 256x128 tile, 3-buffer 1-phase/K-tile =====
// LDS: 3 buffers x 48KB: A[256x64] @0, B[128x64] @32768. 8 waves: 4M x 2N.
// Phase i: read buf i%3 (16 ds_reads), stage tile i+2 -> buf (i+2)%3 (read in phase i-1,
// so write-after-read gap = 1 phase), 32 MFMA, VMC6 (drains tile i+1's 6 needed next).
__global__ __launch_bounds__(512, 2) void gemm2_kernel(
    const __hip_bfloat16* __restrict__ act, const __hip_bfloat16* __restrict__ Wd,
    const int* __restrict__ ofs, float* __restrict__ ybuf) {
  __shared__ __align__(128) char lds[147456];
  const int nwg = gridDim.x;              // 576 (div by 8)
  int wg0 = blockIdx.x;
  int wg = (wg0 & 7) * (nwg >> 3) + (wg0 >> 3);
  const int tm = wg >> 3, tn = wg & 7;    // NTN = 8 (128-col tiles over HD=1024)
  const int Rtot = ofs[NE];
  const int row0 = tm * 256;
  if (row0 >= Rtot) return;
  int e = 0;
#pragma unroll
  for (int i = 1; i < NE; i++) e += (row0 >= ofs[i]);
  const int tid = threadIdx.x, wid = tid >> 6, lane = tid & 63;
  const int wm = wid >> 1, wn = wid & 1;  // 4 M-warps x 2 N-warps
  const int fr = lane & 15, fkE = (lane >> 4) << 3;
  const int wmB = wm * 64, wnB = wn * 64;

  const char* srcA[4]; const char* srcB[2];
  int ldA[4], ldB[2];
#pragma unroll
  for (int j = 0; j < 4; j++) {
    int d = j * 8192 + tid * 16;
    int row = d >> 7;
    int kb = (d ^ (((d >> 7) & 7) << 4)) & 127;
    srcA[j] = (const char*)(act + (size_t)(row0 + row) * ID) + kb;
    ldA[j] = j * 8192 + wid * 1024;
  }
#pragma unroll
  for (int j = 0; j < 2; j++) {
    int d = j * 8192 + tid * 16;
    int row = d >> 7;
    int kb = (d ^ (((d >> 7) & 7) << 4)) & 127;
    srcB[j] = (const char*)(Wd + ((size_t)e * HD + tn * 128 + row) * ID) + kb;
    ldB[j] = 32768 + j * 8192 + wid * 1024;
  }
#define STG_A2(j, t, q) stage16(srcA[j] + (size_t)(t) * 128, (char*)lds + (q) * 49152 + ldA[j])
#define STG_B2(j, t, q) stage16(srcB[j] + (size_t)(t) * 128, (char*)lds + (q) * 49152 + ldB[j])

  auto RD = [&](const char* base, int poff, int rowi, int kki) -> short8v {
    int o = ((rowi + fr) << 7) + ((kki << 5) + fkE) * 2;
    o ^= ((o >> 7) & 7) << 4;
    return *(const short8v*)(base + poff + o);
  };

  f32x4 acc[4][4];
#pragma unroll
  for (int m = 0; m < 4; m++)
#pragma unroll
    for (int n = 0; n < 4; n++) acc[m][n] = (f32x4)(0.0f);

  const int NT = ID / 64;  // 64 K-tiles
  // prologue: tile0 -> buf0 [6], tile1 -> buf1 [6]; VMC6 drains tile0.
#pragma unroll
  for (int j = 0; j < 4; j++) STG_A2(j, 0, 0);
  STG_B2(0, 0, 0); STG_B2(1, 0, 0);
#pragma unroll
  for (int j = 0; j < 4; j++) STG_A2(j, 1, 1);
  STG_B2(0, 1, 1); STG_B2(1, 1, 1);
  VMC6; BARRIER;

  int bq = 0;  // current buffer
#pragma unroll 1
  for (int T = 0; T < NT; ++T) {
    const bool more = (T + 2 < NT);
    int sq = (bq >= 1) ? (bq - 1) : 2;  // (bq+2)%3
    const char* base = (const char*)lds + bq * 49152;
    short8v a[4][2], b[4][2];
#pragma unroll
    for (int m = 0; m < 4; m++) { a[m][0] = RD(base, 0, wmB + m * 16, 0); a[m][1] = RD(base, 0, wmB + m * 16, 1); }
#pragma unroll
    for (int n = 0; n < 4; n++) { b[n][0] = RD(base, 32768, wnB + n * 16, 0); b[n][1] = RD(base, 32768, wnB + n * 16, 1); }
    if (more) {
      STG_A2(0, T + 2, sq); STG_A2(1, T + 2, sq); STG_A2(2, T + 2, sq); STG_A2(3, T + 2, sq);
      STG_B2(0, T + 2, sq); STG_B2(1, T + 2, sq);
    }
    BARRIER; WAITLGKM;
    __builtin_amdgcn_s_setprio(1); MFMA44(acc, a, b); __builtin_amdgcn_s_setprio(0);
    if (more) { VMC6; } else { VMC0; }
    BARRIER;
    bq = (bq == 2) ? 0 : (bq + 1);
  }
#undef STG_A2
#undef STG_B2

  const int rb = row0 + wmB + ((lane >> 4) << 2);
  const int cb = tn * 128 + wnB + fr;
#pragma unroll
  for (int m = 0; m < 4; m++)
#pragma unroll
    for (int i = 0; i < 4; i++) {
      int r = rb + m * 16 + i;
      float* dst = ybuf + (size_t)r * HD + cb;
#pragma unroll
      for (int n = 0; n < 4; n++) dst[n * 16] = acc[m][n][i];
    }
}

// ---------------- combine: out[t] = w0*y[slot0] + w1*y[slot1] ----------------
__global__ __launch_bounds__(256) void combine_kernel(
    const float* __restrict__ ybuf, const int* __restrict__ slots,
    const float* __restrict__ tw, float* __restrict__ out) {
  int t = blockIdx.x * 4 + (threadIdx.x >> 6);
  int lane = threadIdx.x & 63;
  int r0 = slots[t * 2 + 0], r1 = slots[t * 2 + 1];
  float w0 = tw[t * 2 + 0], w1 = tw[t * 2 + 1];
  const float4* y0 = (const float4*)(ybuf + (size_t)r0 * HD);
  const float4* y1 = (const float4*)(ybuf + (size_t)r1 * HD);
  float4* o = (float4*)(out + (size_t)t * HD);
#pragma unroll
  for (int j = 0; j < 4; j++) {
    int ix = j * 64 + lane;
    float4 a = y0[ix], b = y1[ix];
    float4 c;
    c.x = w0 * a.x + w1 * b.x; c.y = w0 * a.y + w1 * b.y;
    c.z = w0 * a.z + w1 * b.z; c.w = w0 * a.w + w1 * b.w;
    o[ix] = c;
  }
}

extern "C" void kernel_launch(void* const* d_in, const int* in_sizes, int n_in,
                              void* d_out, int out_size, void* d_ws, size_t ws_size,
                              hipStream_t stream) {
  (void)in_sizes; (void)n_in; (void)out_size; (void)ws_size;
  const float* h  = (const float*)d_in[0];
  const float* rw = (const float*)d_in[1];
  const float* gw = (const float*)d_in[2];
  const float* uw = (const float*)d_in[3];
  const float* dw = (const float*)d_in[4];
  float* out = (float*)d_out;

  char* ws = (char*)d_ws;
  size_t off = 0;
  auto alloc = [&](size_t bytes) { char* p = ws + off; off += (bytes + 255) & ~255ULL; return p; };
  __hip_bfloat16* wg  = (__hip_bfloat16*)alloc((size_t)NE * ID * HD * 2);
  __hip_bfloat16* wu  = (__hip_bfloat16*)alloc((size_t)NE * ID * HD * 2);
  __hip_bfloat16* wd  = (__hip_bfloat16*)alloc((size_t)NE * HD * ID * 2);
  __hip_bfloat16* act = (__hip_bfloat16*)alloc((size_t)RMAX * ID * 2);
  __hip_bfloat16* hx  = (__hip_bfloat16*)alloc((size_t)TOKENS * HD * 2);
  float* ybuf = (float*)alloc((size_t)RMAX * HD * 4);
  __hip_bfloat16* zrow = (__hip_bfloat16*)alloc(HD * 2);
  int* rowmap = (int*)alloc(RMAX * 4);
  int* tidx   = (int*)alloc(TOKENS * 2 * 4);
  float* twt  = (float*)alloc(TOKENS * 2 * 4);
  int* slots  = (int*)alloc(TOKENS * 2 * 4);
  int* cnt    = (int*)alloc(256);
  int* cnt2   = (int*)alloc(256);
  int* ofs    = (int*)alloc(256);

  hipMemsetAsync(cnt, 0, NE * 4, stream);
  hipMemsetAsync(rowmap, 0xFF, RMAX * 4, stream);
  hipMemsetAsync(zrow, 0, HD * 2, stream);

  convert3_kernel<<<49152, 256, 0, stream>>>(gw, uw, dw, wg);
  router_kernel<<<TOKENS / 4, 256, 0, stream>>>(h, rw, hx, tidx, twt, cnt);
  scan_kernel<<<1, 64, 0, stream>>>(cnt, ofs, cnt2);
  scatter_kernel<<<TOKENS / 256, 256, 0, stream>>>(tidx, twt, ofs, cnt2, rowmap, slots);
  gemm1_kernel<<<MAXT * 32, 512, 0, stream>>>(hx, wg, wu, rowmap, ofs, zrow, act);
  gemm2_kernel<<<MAXT * 8, 512, 0, stream>>>(act, wd, ofs, ybuf);
  combine_kernel<<<TOKENS / 4, 256, 0, stream>>>(ybuf, slots, twt, out);
}